// Round 6
// baseline (150.065 us; speedup 1.0000x reference)
//
#include <hip/hip_runtime.h>
#include <hip/hip_bf16.h>

#define BS  4
#define SEQ 4096
#define DK  128

// p = exp(s_raw / sqrt(128)) = exp2(C1_SCALE * s_raw).  C1_SCALE is folded
// into the bf16 cast of Q (replaces the cast rounding, does not add one), so
// the MFMA output is already in log2 domain: p = exp2(s).
#define C1_SCALE (1.4426950408889634f / 11.313708498984761f)

typedef __attribute__((ext_vector_type(8))) short bf16x8;
typedef __attribute__((ext_vector_type(4))) float f32x4;
typedef __attribute__((ext_vector_type(16))) float f32x16;
typedef unsigned short ushort_t;

__device__ inline unsigned pk_bf16(float a, float b) {
    __hip_bfloat162 h = __float22bfloat162_rn(make_float2(a, b));
    union { __hip_bfloat162 h2; unsigned u; } cv;
    cv.h2 = h;
    return cv.u;
}

__device__ inline bf16x8 pk8(float4 a, float4 b) {
    union { bf16x8 v; unsigned u[4]; } r;
    r.u[0] = pk_bf16(a.x, a.y);
    r.u[1] = pk_bf16(a.z, a.w);
    r.u[2] = pk_bf16(b.x, b.y);
    r.u[3] = pk_bf16(b.z, b.w);
    return r.v;
}

// async global->LDS, 16B per lane; lds base must be wave-uniform
__device__ inline void gld_lds16(const ushort_t* g, ushort_t* l) {
    __builtin_amdgcn_global_load_lds(
        (const __attribute__((address_space(1))) unsigned int*)g,
        (__attribute__((address_space(3))) unsigned int*)l,
        16, 0, 0);
}

__device__ inline void bar_fence() {
    __builtin_amdgcn_s_barrier();
    asm volatile("" ::: "memory");
}

// v_permlane32_swap_b32: x.hi32lanes <-> y.lo32lanes (both regs updated)
__device__ inline void pl32_swap(unsigned &x, unsigned &y) {
    asm volatile("v_permlane32_swap_b32 %0, %1" : "+v"(x), "+v"(y));
}

// ---------------------------------------------------------------------------
// Swizzled-row bf16 cast of Q (x C1_SCALE) and K: row r (256 B = 16 atoms of
// 16 B), atom a stored at position a ^ (r & 15). Linear DMA of 16-row-aligned
// tiles reproduces the swizzled LDS image; fragment reads use atom
// (atom ^ rowbits) -> conflict-free LDS banking.
// ---------------------------------------------------------------------------
__global__ __launch_bounds__(256) void cast_qk_sw(
    const float* __restrict__ Q, const float* __restrict__ K,
    ushort_t* __restrict__ Qb, ushort_t* __restrict__ Kb)
{
    const int g = blockIdx.x * 256 + threadIdx.x;   // atom id
    const int q = g >> 4, ap = g & 15;
    const int a = ap ^ (q & 15);
    const float* src = Q + (size_t)q * DK + a * 8;
    float4 x = *(const float4*)src, y = *(const float4*)(src + 4);
    x.x *= C1_SCALE; x.y *= C1_SCALE; x.z *= C1_SCALE; x.w *= C1_SCALE;
    y.x *= C1_SCALE; y.y *= C1_SCALE; y.z *= C1_SCALE; y.w *= C1_SCALE;
    *(bf16x8*)(Qb + (size_t)g * 8) = pk8(x, y);
    src = K + (size_t)q * DK + a * 8;
    float4 x2 = *(const float4*)src, y2 = *(const float4*)(src + 4);
    *(bf16x8*)(Kb + (size_t)g * 8) = pk8(x2, y2);
}

// ---------------------------------------------------------------------------
// Pass 1: l[b,k] partials = sum_q exp(s_qk).  Triple-buffered Q tiles via
// global_load_lds with COUNTED vmcnt (never 0 in-loop).  Unchanged (works).
// ---------------------------------------------------------------------------
__global__ __launch_bounds__(256) void sdpa_lsum(
    const ushort_t* __restrict__ Qb, const ushort_t* __restrict__ Kb,
    float* __restrict__ lp)
{
    __shared__ ushort_t Qs[3][4096];   // 3 x (32 q x 128 dk), swizzled rows

    const int kt = blockIdx.x, qs = blockIdx.y, b = blockIdx.z;
    const int tid = threadIdx.x;
    const int w = tid >> 6, lane = tid & 63, ln = lane & 15, quad = lane >> 4;

    bf16x8 ka[2][4];
#pragma unroll
    for (int mt = 0; mt < 2; ++mt)
#pragma unroll
        for (int c = 0; c < 4; ++c)
            ka[mt][c] = *(const bf16x8*)(Kb +
                ((size_t)(b * SEQ) + kt * 128 + w * 32 + mt * 16 + ln) * DK +
                (((c * 4 + quad) ^ ln) * 8));

    float ls[2][4] = {};
    const ushort_t* qtb = Qb + ((size_t)(b * SEQ + qs * 512)) * DK;

#define A_DMA(BUF, I)                                                          \
    {                                                                          \
        _Pragma("unroll")                                                      \
        for (int j = 0; j < 2; ++j)                                            \
            gld_lds16(qtb + (size_t)(I) * 4096 + (j * 256 + tid) * 8,          \
                      &Qs[BUF][(j * 256 + w * 64) * 8]);                       \
    }

#define A_CMP(BUF)                                                             \
    {                                                                          \
        bf16x8 qf[2][4];                                                       \
        _Pragma("unroll")                                                      \
        for (int nt = 0; nt < 2; ++nt)                                         \
            _Pragma("unroll")                                                  \
            for (int c = 0; c < 4; ++c)                                        \
                qf[nt][c] = *(const bf16x8*)&Qs[BUF][(nt * 16 + ln) * 128 +    \
                                    (((c * 4 + quad) ^ ln) * 8)];              \
        _Pragma("unroll")                                                      \
        for (int mt = 0; mt < 2; ++mt)                                         \
            _Pragma("unroll")                                                  \
            for (int nt = 0; nt < 2; ++nt) {                                   \
                f32x4 s = {0.f, 0.f, 0.f, 0.f};                                \
                __builtin_amdgcn_s_setprio(1);                                 \
                _Pragma("unroll")                                              \
                for (int c = 0; c < 4; ++c)                                    \
                    s = __builtin_amdgcn_mfma_f32_16x16x32_bf16(               \
                        ka[mt][c], qf[nt][c], s, 0, 0, 0);                     \
                __builtin_amdgcn_s_setprio(0);                                 \
                _Pragma("unroll")                                              \
                for (int r = 0; r < 4; ++r)                                    \
                    ls[mt][r] += __builtin_amdgcn_exp2f(s[r]);                 \
            }                                                                  \
    }

    A_DMA(0, 0)
    A_DMA(1, 1)
    for (int t = 0; t < 15; ++t) {
        asm volatile("s_waitcnt vmcnt(2) lgkmcnt(0)" ::: "memory");
        bar_fence();
        if (t < 14) A_DMA((t + 2) % 3, t + 2)
        A_CMP(t % 3)
    }
    asm volatile("s_waitcnt vmcnt(0) lgkmcnt(0)" ::: "memory");
    bar_fence();
    A_CMP(0)
#undef A_DMA
#undef A_CMP

#pragma unroll
    for (int mt = 0; mt < 2; ++mt)
#pragma unroll
        for (int r = 0; r < 4; ++r) {
            float vv = ls[mt][r];
            vv += __shfl_xor(vv, 1);
            vv += __shfl_xor(vv, 2);
            vv += __shfl_xor(vv, 4);
            vv += __shfl_xor(vv, 8);
            ls[mt][r] = vv;
        }
    if (ln < 8) {
        int k = kt * 128 + w * 32 + (ln >> 2) * 16 + quad * 4 + (ln & 3);
        lp[((size_t)(qs * BS + b)) * SEQ + k] = ls[ln >> 2][ln & 3];
    }
}

// ---------------------------------------------------------------------------
// VbT[b][d][k] = bf16( V[b][k][d] / l[b][k] ), l = sum of 8 qs-partials.
// ---------------------------------------------------------------------------
__global__ __launch_bounds__(256) void vb_transpose(
    const float* __restrict__ V, const float* __restrict__ lp,
    ushort_t* __restrict__ VbT)
{
    __shared__ float Vl[64][132];
    __shared__ float Wl[64];

    const int kt = blockIdx.x, b = blockIdx.y;
    const int tid = threadIdx.x;
    const int k0 = kt * 64;
    {
        int r = tid >> 2, sg = tid & 3;
        const float* src = V + ((size_t)(b * SEQ) + k0 + r) * DK + sg * 32;
#pragma unroll
        for (int i = 0; i < 8; ++i)
            *(float4*)&Vl[r][sg * 32 + i * 4] = *(const float4*)(src + i * 4);
    }
    if (tid < 64) {
        float s = 0.f;
#pragma unroll
        for (int qs = 0; qs < 8; ++qs)
            s += lp[((size_t)(qs * BS + b)) * SEQ + k0 + tid];
        Wl[tid] = 1.0f / s;
    }
    __syncthreads();

    const int d = tid >> 1, kh = tid & 1;
    unsigned u[16];
#pragma unroll
    for (int j = 0; j < 16; ++j) {
        int row = kh * 32 + j * 2;
        u[j] = pk_bf16(Vl[row][d] * Wl[row], Vl[row + 1][d] * Wl[row + 1]);
    }
    ushort_t* dst = VbT + ((size_t)(b * DK) + d) * SEQ + k0 + kh * 32;
#pragma unroll
    for (int i = 0; i < 4; ++i) {
        uint4 t4; t4.x = u[i*4]; t4.y = u[i*4+1]; t4.z = u[i*4+2]; t4.w = u[i*4+3];
        *(uint4*)(dst + i * 8) = t4;
    }
}

// ---------------------------------------------------------------------------
// Pass 2: O_partial[ks] = exp(QK^T) . V'  — T12 restructure: 32x32x16 MFMA,
// P ENTIRELY IN REGISTERS (no P LDS bounce, no cross-wave P handoff).
// Each wave owns 32 q-rows (block = 4 waves = 128 q).  Per 64-k tile,
// per 32-k subtile: QK mfma(A=K, B=Q) -> P[k][q=lane] lane-local (C layout
// col=lane&31, row=(reg&3)+8(reg>>2)+4hi) -> exp2 -> pk_bf16 -> 4x
// v_permlane32_swap_b32 redistributes hi/lo k-halves so each lane holds the
// 8 consecutive k's of its PV B-frag -> PV mfma(A=V', B=P) accumulates
// O^T[d][q=lane].  K/V staged via global_load_lds (K: cast-time row swizzle;
// V: atom^(d&7) pre-swizzled source) -> all LDS frag reads conflict-free.
// Barriers only gate K/V buffer recycling (2/tile); counted vmcnt keeps the
// next tile's 8 loads in flight.
// grid (x=16 (ks,b), y=32 qt(128q)), 256 thr, 64 KB LDS -> 2 blocks/CU.
// ---------------------------------------------------------------------------
__global__ __launch_bounds__(256, 2) void sdpa_out(
    const ushort_t* __restrict__ Qb, const ushort_t* __restrict__ Kb,
    const ushort_t* __restrict__ VbT,
    float* __restrict__ Op, float* __restrict__ O, int use_partial)
{
    __shared__ ushort_t Kt[2][64 * 128];   // 64 k x 128 dk (swizzled rows, 256B)
    __shared__ ushort_t Vt[2][128 * 64];   // 128 d x 64 k  (atom^(d&7), 128B rows)

    const int g  = blockIdx.x;
    const int qt = blockIdx.y;
    const int ks = g >> 2, b = g & 3;
    const int tid = threadIdx.x;
    const int w = tid >> 6, lane = tid & 63;
    const int l31 = lane & 31, hi = lane >> 5;
    const int vdn = tid >> 3, van = tid & 7;   // V-DMA thread coords

    // stationary Q B-frags: lane l: Q[qrow][dk = m*16 + hi*8 + j], swizzled
    const int qrow = qt * 128 + w * 32 + l31;
    const ushort_t* qb = Qb + ((size_t)(b * SEQ) + qrow) * DK;
    bf16x8 qa[8];
#pragma unroll
    for (int m = 0; m < 8; ++m)
        qa[m] = *(const bf16x8*)(qb + (((2 * m + hi) ^ (qrow & 15)) * 8));

    f32x16 acc[4];
#pragma unroll
    for (int i = 0; i < 4; ++i)
#pragma unroll
        for (int r = 0; r < 16; ++r) acc[i][r] = 0.f;

    const ushort_t* ksrc = Kb + ((size_t)(b * SEQ) + ks * 1024) * DK;
    const ushort_t* vsrc = VbT + ((size_t)(b * DK)) * SEQ + ks * 1024;

// K tile: 64 rows x 256 B, position-linear copy (cast swizzle preserved)
// V tile: 128 rows x 128 B, source pre-swizzled (pos p holds atom p^(d&7))
#define DMA_KV(BUF, T)                                                         \
    {                                                                          \
        _Pragma("unroll")                                                      \
        for (int j = 0; j < 4; ++j)                                            \
            gld_lds16(ksrc + (size_t)(T) * 64 * DK + (j * 256 + tid) * 8,      \
                      &Kt[BUF][(j * 256 + w * 64) * 8]);                       \
        _Pragma("unroll")                                                      \
        for (int j = 0; j < 4; ++j)                                            \
            gld_lds16(vsrc + (size_t)(j * 32 + vdn) * SEQ + (T) * 64 +         \
                          ((van ^ (vdn & 7)) * 8),                             \
                      &Vt[BUF][(j * 256 + w * 64) * 8]);                       \
    }

// one 32-k subtile S of tile in BUF: QK (8 MFMA, split 4+4 accumulators) ->
// softmax/cvt (16 add + 16 exp2 + 8 pk) -> permlane redistribute (4 swaps)
// -> PV (8 ds_read + 8 MFMA into acc).
#define SUBTILE(BUF, S)                                                        \
    {                                                                          \
        bf16x8 kf[8];                                                          \
        _Pragma("unroll")                                                      \
        for (int m = 0; m < 8; ++m)                                            \
            kf[m] = *(const bf16x8*)&Kt[BUF][((S) * 32 + l31) * 128 +          \
                        (((2 * m + hi) ^ (l31 & 15)) * 8)];                    \
        f32x16 pA, pB;                                                         \
        _Pragma("unroll")                                                      \
        for (int r = 0; r < 16; ++r) { pA[r] = 0.f; pB[r] = 0.f; }             \
        __builtin_amdgcn_s_setprio(1);                                         \
        _Pragma("unroll")                                                      \
        for (int m = 0; m < 4; ++m)                                            \
            pA = __builtin_amdgcn_mfma_f32_32x32x16_bf16(kf[m], qa[m], pA, 0, 0, 0); \
        _Pragma("unroll")                                                      \
        for (int m = 0; m < 4; ++m)                                            \
            pB = __builtin_amdgcn_mfma_f32_32x32x16_bf16(kf[m + 4], qa[m + 4], pB, 0, 0, 0); \
        __builtin_amdgcn_s_setprio(0);                                         \
        unsigned wv[8];                                                        \
        _Pragma("unroll")                                                      \
        for (int j = 0; j < 8; ++j) {                                          \
            float e0 = __builtin_amdgcn_exp2f(pA[2 * j]     + pB[2 * j]);      \
            float e1 = __builtin_amdgcn_exp2f(pA[2 * j + 1] + pB[2 * j + 1]);  \
            wv[j] = pk_bf16(e0, e1);                                           \
        }                                                                      \
        pl32_swap(wv[0], wv[2]); pl32_swap(wv[1], wv[3]);                      \
        pl32_swap(wv[4], wv[6]); pl32_swap(wv[5], wv[7]);                      \
        bf16x8 pa0, pa1;                                                       \
        { union { unsigned u[4]; bf16x8 v; } c;                                \
          c.u[0] = wv[0]; c.u[1] = wv[1]; c.u[2] = wv[2]; c.u[3] = wv[3];      \
          pa0 = c.v;                                                           \
          c.u[0] = wv[4]; c.u[1] = wv[5]; c.u[2] = wv[6]; c.u[3] = wv[7];      \
          pa1 = c.v; }                                                         \
        _Pragma("unroll")                                                      \
        for (int dt = 0; dt < 4; ++dt) {                                       \
            bf16x8 v0 = *(const bf16x8*)&Vt[BUF][(dt * 32 + l31) * 64 +        \
                            ((((S) * 4 + 0 + hi) ^ (l31 & 7)) * 8)];           \
            bf16x8 v1 = *(const bf16x8*)&Vt[BUF][(dt * 32 + l31) * 64 +        \
                            ((((S) * 4 + 2 + hi) ^ (l31 & 7)) * 8)];           \
            __builtin_amdgcn_s_setprio(1);                                     \
            acc[dt] = __builtin_amdgcn_mfma_f32_32x32x16_bf16(v0, pa0, acc[dt], 0, 0, 0); \
            acc[dt] = __builtin_amdgcn_mfma_f32_32x32x16_bf16(v1, pa1, acc[dt], 0, 0, 0); \
            __builtin_amdgcn_s_setprio(0);                                     \
        }                                                                      \
    }

    DMA_KV(0, 0)
    DMA_KV(1, 1)

    for (int t = 0; t < 16; ++t) {
        if (t < 15) asm volatile("s_waitcnt vmcnt(8)" ::: "memory");
        else        asm volatile("s_waitcnt vmcnt(0)" ::: "memory");
        bar_fence();                    // buf[t&1] ready (next tile in flight)
        SUBTILE(t & 1, 0)
        SUBTILE(t & 1, 1)
        bar_fence();                    // all waves done reading buf[t&1]
        if (t < 14) DMA_KV(t & 1, t + 2)
    }
#undef DMA_KV
#undef SUBTILE

    // acc[dt] reg r -> O^T[d][q=qrow], d = dt*32 + (r&3) + 8*(r>>2) + 4*hi
    if (use_partial) {
        float* dst = Op + (size_t)ks * ((size_t)BS * SEQ * DK) +
                     ((size_t)(b * SEQ) + qrow) * DK;
#pragma unroll
        for (int dt = 0; dt < 4; ++dt)
#pragma unroll
            for (int gg = 0; gg < 4; ++gg) {
                float4 v4;
                v4.x = acc[dt][gg * 4 + 0];
                v4.y = acc[dt][gg * 4 + 1];
                v4.z = acc[dt][gg * 4 + 2];
                v4.w = acc[dt][gg * 4 + 3];
                *(float4*)(dst + dt * 32 + gg * 8 + hi * 4) = v4;
            }
    } else {
        float* dst = O + ((size_t)(b * SEQ) + qrow) * DK;
#pragma unroll
        for (int dt = 0; dt < 4; ++dt)
#pragma unroll
            for (int gg = 0; gg < 4; ++gg)
#pragma unroll
                for (int i = 0; i < 4; ++i)
                    atomicAdd(dst + dt * 32 + gg * 8 + hi * 4 + i,
                              acc[dt][gg * 4 + i]);
    }
}

// ---------------------------------------------------------------------------
// reduce4: O = sum of 4 k-split partials (float4 per thread).
// ---------------------------------------------------------------------------
__global__ __launch_bounds__(256) void reduce4(
    const float* __restrict__ Op, float* __restrict__ O)
{
    const size_t N = (size_t)BS * SEQ * DK;
    size_t i = ((size_t)blockIdx.x * 256 + threadIdx.x) * 4;
    float4 a0 = *(const float4*)(Op + i);
    float4 a1 = *(const float4*)(Op + N + i);
    float4 a2 = *(const float4*)(Op + 2 * N + i);
    float4 a3 = *(const float4*)(Op + 3 * N + i);
    float4 r;
    r.x = a0.x + a1.x + a2.x + a3.x;
    r.y = a0.y + a1.y + a2.y + a3.y;
    r.z = a0.z + a1.z + a2.z + a3.z;
    r.w = a0.w + a1.w + a2.w + a3.w;
    *(float4*)(O + i) = r;
}

extern "C" void kernel_launch(void* const* d_in, const int* in_sizes, int n_in,
                              void* d_out, int out_size, void* d_ws, size_t ws_size,
                              hipStream_t stream) {
    const float* q = (const float*)d_in[0];
    const float* k = (const float*)d_in[1];
    const float* v = (const float*)d_in[2];
    float* out = (float*)d_out;

    const size_t QKV = (size_t)BS * SEQ * DK;           // 2 M elements
    float*    lp  = (float*)d_ws;                       // 512 KB used
    ushort_t* Qb  = (ushort_t*)((char*)d_ws + (1 << 20));
    ushort_t* Kb  = Qb + QKV;
    ushort_t* VbT = Kb + QKV;
    float*    Op  = (float*)(VbT + QKV);                // 33.6 MB (4 k-splits)

    const size_t need_p = (1u << 20) + 3 * QKV * 2 + 4 * QKV * sizeof(float);

    cast_qk_sw<<<dim3(BS * SEQ * 16 / 256), 256, 0, stream>>>(q, k, Qb, Kb);
    sdpa_lsum  <<<dim3(32, 8, 4), 256, 0, stream>>>(Qb, Kb, lp);
    vb_transpose<<<dim3(64, 4),   256, 0, stream>>>(v, lp, VbT);

    if (ws_size >= need_p) {
        sdpa_out<<<dim3(16, 32), 256, 0, stream>>>(Qb, Kb, VbT, Op, out, 1);
        reduce4<<<dim3(BS * SEQ * DK / 4 / 256), 256, 0, stream>>>(Op, out);
    } else {
        hipMemsetAsync(out, 0, QKV * sizeof(float), stream);
        sdpa_out<<<dim3(16, 32), 256, 0, stream>>>(Qb, Kb, VbT, nullptr, out, 0);
    }
}